// Round 3
// baseline (1366.491 us; speedup 1.0000x reference)
//
#include <hip/hip_runtime.h>
#include <hip/hip_bf16.h>

// Problem constants (from the reference)
constexpr int NU = 80000;    // users
constexpr int NI = 40000;    // items
constexpr int K  = 64;       // feature dim (== wavefront size, 1 lane per k)
constexpr int NL = 3;        // layers
constexpr int NN = NU + NI;  // 120000 nodes
constexpr int NE = 1000000;  // edges (undirected; each contributes both dirs)
constexpr float EPS   = 1e-12f;
constexpr float SLOPE = 0.01f;

constexpr int SCAN_B = 256;
constexpr int NBLK   = (NN + SCAN_B - 1) / SCAN_B;   // 469 scan blocks

// ---------------------------------------------------------------------------
// Kernel 1: e0 = l2norm(concat(Gu, Gi)); gsum[n] = rowsum(e0)
// ---------------------------------------------------------------------------
__global__ __launch_bounds__(256)
void norm_init_kernel(const float* __restrict__ Gu, const float* __restrict__ Gi,
                      float* __restrict__ e, float* __restrict__ gsum) {
    int node = blockIdx.x * 4 + (threadIdx.x >> 6);
    int lane = threadIdx.x & 63;
    if (node >= NN) return;
    float v = (node < NU) ? Gu[node * K + lane] : Gi[(node - NU) * K + lane];
    float ss = v * v;
    #pragma unroll
    for (int off = 32; off > 0; off >>= 1) ss += __shfl_xor(ss, off);
    float r = v / fmaxf(sqrtf(ss), EPS);
    e[node * K + lane] = r;
    float rs = r;
    #pragma unroll
    for (int off = 32; off > 0; off >>= 1) rs += __shfl_xor(rs, off);
    if (lane == 0) gsum[node] = rs;   // overwrite poison
}

// ---------------------------------------------------------------------------
// CSR build: histogram -> hierarchical exclusive scan -> ticket fill.
// ---------------------------------------------------------------------------
__global__ __launch_bounds__(256)
void hist_kernel(const int* __restrict__ eu, const int* __restrict__ ei,
                 int* __restrict__ rowptr) {
    int e = blockIdx.x * blockDim.x + threadIdx.x;
    if (e >= NE) return;
    atomicAdd(&rowptr[1 + eu[e]], 1);
    atomicAdd(&rowptr[1 + ei[e]], 1);
}

__global__ __launch_bounds__(SCAN_B)
void scan1_kernel(int* __restrict__ cnt, int* __restrict__ bsum) {
    __shared__ int sh[SCAN_B];
    int i = blockIdx.x * SCAN_B + threadIdx.x;
    int v = (i < NN) ? cnt[i] : 0;
    sh[threadIdx.x] = v;
    __syncthreads();
    #pragma unroll
    for (int off = 1; off < SCAN_B; off <<= 1) {
        int t = (threadIdx.x >= off) ? sh[threadIdx.x - off] : 0;
        __syncthreads();
        sh[threadIdx.x] += t;
        __syncthreads();
    }
    if (i < NN) cnt[i] = sh[threadIdx.x];
    if (threadIdx.x == SCAN_B - 1) bsum[blockIdx.x] = sh[SCAN_B - 1];
}

__global__ __launch_bounds__(512)
void scan2_kernel(int* __restrict__ bsum) {
    __shared__ int sh[512];
    int v = (threadIdx.x < NBLK) ? bsum[threadIdx.x] : 0;
    sh[threadIdx.x] = v;
    __syncthreads();
    #pragma unroll
    for (int off = 1; off < 512; off <<= 1) {
        int t = (threadIdx.x >= off) ? sh[threadIdx.x - off] : 0;
        __syncthreads();
        sh[threadIdx.x] += t;
        __syncthreads();
    }
    if (threadIdx.x < NBLK) bsum[threadIdx.x] = sh[threadIdx.x] - v; // exclusive
}

__global__ __launch_bounds__(SCAN_B)
void scan3_kernel(int* __restrict__ rowptr, const int* __restrict__ bsum,
                  int* __restrict__ cursor) {
    int i = blockIdx.x * SCAN_B + threadIdx.x;   // index into cnt = rowptr+1
    if (i < NN) {
        int v = rowptr[1 + i] + bsum[blockIdx.x];
        rowptr[1 + i] = v;                        // rowptr[i+1] final
        if (i + 1 < NN) cursor[i + 1] = v;        // start of node i+1
    }
    if (i == 0) cursor[0] = 0;
}

__global__ __launch_bounds__(256)
void fill_kernel(const int* __restrict__ eu, const int* __restrict__ ei,
                 int* __restrict__ cursor, int* __restrict__ cols) {
    int e = blockIdx.x * blockDim.x + threadIdx.x;
    if (e >= NE) return;
    int u = eu[e];
    int i = ei[e];
    int p = atomicAdd(&cursor[u], 1);
    cols[p] = i;
    int q = atomicAdd(&cursor[i], 1);
    cols[q] = u;
}

// ---------------------------------------------------------------------------
// Fused layer: gather-SpMM + dense transform + activation + l2norm + rowsum.
//   side = sum_{j in adj(n)} x[j]   (registers, no side buffer)
//   p = side + x ; q = side * x
//   h = p@W1 + b1 + q@W2 + b2 ; y = l2norm(leaky_relu(h)) ; gsum += rowsum(y)
// One wave per node. Weight column `lane` of W1/W2 lives in VGPRs (128 regs);
// p[j]/q[j] broadcast via __shfl with compile-time j -> v_readlane + SGPR-FMA.
// No LDS at all. Grid-stride to amortize the weight preload.
// ---------------------------------------------------------------------------
__global__ __launch_bounds__(256, 2)
void fused_layer_kernel(const int* __restrict__ rowptr, const int* __restrict__ cols,
                        const float* __restrict__ x,
                        const float* __restrict__ W1, const float* __restrict__ b1,
                        const float* __restrict__ W2, const float* __restrict__ b2,
                        float* __restrict__ y, float* __restrict__ gsum) {
    const int wave = threadIdx.x >> 6;
    const int lane = threadIdx.x & 63;

    // Per-lane weight columns: w1c[j] = W1[j][lane]  (stays in registers;
    // all indexing is compile-time after full unroll)
    float w1c[K], w2c[K];
    #pragma unroll
    for (int j = 0; j < K; ++j) {
        w1c[j] = W1[j * K + lane];
        w2c[j] = W2[j * K + lane];
    }
    const float bias = b1[lane] + b2[lane];

    for (int node = blockIdx.x * 4 + wave; node < NN; node += gridDim.x * 4) {
        // --- gather: side = sum of neighbor rows (4 loads in flight) ---
        int s = rowptr[node];
        int e = rowptr[node + 1];
        float a0 = 0.f, a1 = 0.f, a2 = 0.f, a3 = 0.f;
        int t = s;
        for (; t + 4 <= e; t += 4) {
            int n0 = cols[t];
            int n1 = cols[t + 1];
            int n2 = cols[t + 2];
            int n3 = cols[t + 3];
            a0 += x[(size_t)n0 * K + lane];
            a1 += x[(size_t)n1 * K + lane];
            a2 += x[(size_t)n2 * K + lane];
            a3 += x[(size_t)n3 * K + lane];
        }
        for (; t < e; ++t) a0 += x[(size_t)cols[t] * K + lane];
        float sv = (a0 + a1) + (a2 + a3);

        // --- dense transform (lane j holds p[j]; broadcast via readlane) ---
        float xv = x[(size_t)node * K + lane];
        float p = sv + xv;
        float q = sv * xv;
        float acc = bias;
        #pragma unroll
        for (int j = 0; j < K; ++j) {
            acc = fmaf(__shfl(p, j), w1c[j], acc);
            acc = fmaf(__shfl(q, j), w2c[j], acc);
        }

        // --- leaky relu + l2norm + rowsum ---
        float h = (acc > 0.f) ? acc : SLOPE * acc;
        float ss = h * h;
        #pragma unroll
        for (int off = 32; off > 0; off >>= 1) ss += __shfl_xor(ss, off);
        float r = h / fmaxf(sqrtf(ss), EPS);
        y[(size_t)node * K + lane] = r;
        float rs = r;
        #pragma unroll
        for (int off = 32; off > 0; off >>= 1) rs += __shfl_xor(rs, off);
        if (lane == 0) gsum[node] += rs;   // one wave per node: no race
    }
}

// ---------------------------------------------------------------------------
// out[n] = gsum[n] / ((L+1)*K) = gsum[n] / 256
// ---------------------------------------------------------------------------
__global__ __launch_bounds__(256)
void finalize_kernel(const float* __restrict__ gsum, float* __restrict__ out) {
    int n = blockIdx.x * blockDim.x + threadIdx.x;
    if (n < NN) out[n] = gsum[n] * (1.0f / ((NL + 1) * K));
}

extern "C" void kernel_launch(void* const* d_in, const int* in_sizes, int n_in,
                              void* d_out, int out_size, void* d_ws, size_t ws_size,
                              hipStream_t stream) {
    const float* Gu = (const float*)d_in[0];
    const float* Gi = (const float*)d_in[1];
    const float* W1 = (const float*)d_in[2];   // [NL][K][K]
    const float* b1 = (const float*)d_in[3];   // [NL][K]
    const float* W2 = (const float*)d_in[4];
    const float* b2 = (const float*)d_in[5];
    const int*  edge = (const int*)d_in[6];    // [2][NE]
    float* out = (float*)d_out;

    // Workspace layout (4B elems): ebuf0 | ebuf1 | gsum | rowptr | bsum | cursor | cols
    float* ebuf0  = (float*)d_ws;
    float* ebuf1  = ebuf0 + (size_t)NN * K;
    float* gsum   = ebuf1 + (size_t)NN * K;
    int*   rowptr = (int*)(gsum + NN);
    int*   bsum   = rowptr + (NN + 1);
    int*   cursor = bsum + 512;
    int*   cols   = cursor + NN;

    const int* eu = edge;
    const int* ei = edge + NE;

    // --- CSR build (once per launch) ---
    hipMemsetAsync(rowptr, 0, (size_t)(NN + 1) * sizeof(int), stream);
    hist_kernel <<<(NE + 255) / 256, 256, 0, stream>>>(eu, ei, rowptr);
    scan1_kernel<<<NBLK, SCAN_B, 0, stream>>>(rowptr + 1, bsum);
    scan2_kernel<<<1, 512, 0, stream>>>(bsum);
    scan3_kernel<<<NBLK, SCAN_B, 0, stream>>>(rowptr, bsum, cursor);
    fill_kernel <<<(NE + 255) / 256, 256, 0, stream>>>(eu, ei, cursor, cols);

    // --- embeddings ---
    norm_init_kernel<<<(NN + 3) / 4, 256, 0, stream>>>(Gu, Gi, ebuf0, gsum);

    float* cur = ebuf0;
    float* nxt = ebuf1;
    for (int l = 0; l < NL; ++l) {
        fused_layer_kernel<<<2048, 256, 0, stream>>>(rowptr, cols, cur,
                                                     W1 + (size_t)l * K * K, b1 + (size_t)l * K,
                                                     W2 + (size_t)l * K * K, b2 + (size_t)l * K,
                                                     nxt, gsum);
        float* t = cur; cur = nxt; nxt = t;
    }

    finalize_kernel<<<(NN + 255) / 256, 256, 0, stream>>>(gsum, out);
}

// Round 5
// 1202.598 us; speedup vs baseline: 1.1363x; 1.1363x over previous
//
#include <hip/hip_runtime.h>
#include <hip/hip_bf16.h>

// Problem constants (from the reference)
constexpr int NU = 80000;    // users
constexpr int NI = 40000;    // items
constexpr int K  = 64;       // feature dim (== wavefront size, 1 lane per k)
constexpr int NL = 3;        // layers
constexpr int NN = NU + NI;  // 120000 nodes
constexpr int NE = 1000000;  // edges (undirected; each contributes both dirs)
constexpr float EPS   = 1e-12f;
constexpr float SLOPE = 0.01f;

constexpr int SCAN_B = 256;
constexpr int NBLK   = (NN + SCAN_B - 1) / SCAN_B;   // 469 scan blocks

// ---------------------------------------------------------------------------
// Kernel 1: e0 = l2norm(concat(Gu, Gi)); gsum[n] = rowsum(e0)
// ---------------------------------------------------------------------------
__global__ __launch_bounds__(256)
void norm_init_kernel(const float* __restrict__ Gu, const float* __restrict__ Gi,
                      float* __restrict__ e, float* __restrict__ gsum) {
    int node = blockIdx.x * 4 + (threadIdx.x >> 6);
    int lane = threadIdx.x & 63;
    if (node >= NN) return;
    float v = (node < NU) ? Gu[node * K + lane] : Gi[(node - NU) * K + lane];
    float ss = v * v;
    #pragma unroll
    for (int off = 32; off > 0; off >>= 1) ss += __shfl_xor(ss, off);
    float r = v / fmaxf(sqrtf(ss), EPS);
    e[node * K + lane] = r;
    float rs = r;
    #pragma unroll
    for (int off = 32; off > 0; off >>= 1) rs += __shfl_xor(rs, off);
    if (lane == 0) gsum[node] = rs;   // overwrite poison
}

// ---------------------------------------------------------------------------
// CSR build: histogram -> hierarchical exclusive scan -> ticket fill.
// ---------------------------------------------------------------------------
__global__ __launch_bounds__(256)
void hist_kernel(const int* __restrict__ eu, const int* __restrict__ ei,
                 int* __restrict__ rowptr) {
    int e = blockIdx.x * blockDim.x + threadIdx.x;
    if (e >= NE) return;
    atomicAdd(&rowptr[1 + eu[e]], 1);
    atomicAdd(&rowptr[1 + ei[e]], 1);
}

__global__ __launch_bounds__(SCAN_B)
void scan1_kernel(int* __restrict__ cnt, int* __restrict__ bsum) {
    __shared__ int sh[SCAN_B];
    int i = blockIdx.x * SCAN_B + threadIdx.x;
    int v = (i < NN) ? cnt[i] : 0;
    sh[threadIdx.x] = v;
    __syncthreads();
    #pragma unroll
    for (int off = 1; off < SCAN_B; off <<= 1) {
        int t = (threadIdx.x >= off) ? sh[threadIdx.x - off] : 0;
        __syncthreads();
        sh[threadIdx.x] += t;
        __syncthreads();
    }
    if (i < NN) cnt[i] = sh[threadIdx.x];
    if (threadIdx.x == SCAN_B - 1) bsum[blockIdx.x] = sh[SCAN_B - 1];
}

__global__ __launch_bounds__(512)
void scan2_kernel(int* __restrict__ bsum) {
    __shared__ int sh[512];
    int v = (threadIdx.x < NBLK) ? bsum[threadIdx.x] : 0;
    sh[threadIdx.x] = v;
    __syncthreads();
    #pragma unroll
    for (int off = 1; off < 512; off <<= 1) {
        int t = (threadIdx.x >= off) ? sh[threadIdx.x - off] : 0;
        __syncthreads();
        sh[threadIdx.x] += t;
        __syncthreads();
    }
    if (threadIdx.x < NBLK) bsum[threadIdx.x] = sh[threadIdx.x] - v; // exclusive
}

__global__ __launch_bounds__(SCAN_B)
void scan3_kernel(int* __restrict__ rowptr, const int* __restrict__ bsum,
                  int* __restrict__ cursor) {
    int i = blockIdx.x * SCAN_B + threadIdx.x;   // index into cnt = rowptr+1
    if (i < NN) {
        int v = rowptr[1 + i] + bsum[blockIdx.x];
        rowptr[1 + i] = v;                        // rowptr[i+1] final
        if (i + 1 < NN) cursor[i + 1] = v;        // start of node i+1
    }
    if (i == 0) cursor[0] = 0;
}

__global__ __launch_bounds__(256)
void fill_kernel(const int* __restrict__ eu, const int* __restrict__ ei,
                 int* __restrict__ cursor, int* __restrict__ cols) {
    int e = blockIdx.x * blockDim.x + threadIdx.x;
    if (e >= NE) return;
    int u = eu[e];
    int i = ei[e];
    int p = atomicAdd(&cursor[u], 1);
    cols[p] = i;
    int q = atomicAdd(&cursor[i], 1);
    cols[q] = u;
}

// ---------------------------------------------------------------------------
// Gather SpMM: side[n] = sum_{j in adj(n)} x[j].  One wave per node, no
// atomics, write-once. 4 VGPR -> ~max occupancy; TLP hides L2/L3 miss latency.
// ---------------------------------------------------------------------------
__global__ __launch_bounds__(256)
void gather_kernel(const int* __restrict__ rowptr, const int* __restrict__ cols,
                   const float* __restrict__ x, float* __restrict__ side) {
    int node = blockIdx.x * 4 + (threadIdx.x >> 6);
    int lane = threadIdx.x & 63;
    if (node >= NN) return;
    int s = rowptr[node];
    int e = rowptr[node + 1];
    float a0 = 0.f, a1 = 0.f, a2 = 0.f, a3 = 0.f;
    int t = s;
    for (; t + 4 <= e; t += 4) {
        int n0 = cols[t];
        int n1 = cols[t + 1];
        int n2 = cols[t + 2];
        int n3 = cols[t + 3];
        a0 += x[(size_t)n0 * K + lane];
        a1 += x[(size_t)n1 * K + lane];
        a2 += x[(size_t)n2 * K + lane];
        a3 += x[(size_t)n3 * K + lane];
    }
    for (; t < e; ++t) a0 += x[(size_t)cols[t] * K + lane];
    side[(size_t)node * K + lane] = (a0 + a1) + (a2 + a3);
}

// ---------------------------------------------------------------------------
// Dense layer, register-GEMV version (streaming, no LDS):
//   p = side + x ; q = side * x
//   h = p@W1 + b1 + q@W2 + b2 ; y = l2norm(leaky_relu(h)) ; gsum += rowsum(y)
// Lane holds weight columns W1[:,lane], W2[:,lane] in 128 VGPRs; p[j]/q[j]
// broadcast via __shfl with compile-time j -> v_readlane + SGPR-operand FMA.
// ~3-4 waves/SIMD is ample for a sequential-access streaming kernel.
// ---------------------------------------------------------------------------
__global__ __launch_bounds__(256)
void layer_kernel(const float* __restrict__ x, const float* __restrict__ side,
                  const float* __restrict__ W1, const float* __restrict__ b1,
                  const float* __restrict__ W2, const float* __restrict__ b2,
                  float* __restrict__ y, float* __restrict__ gsum) {
    const int wave = threadIdx.x >> 6;
    const int lane = threadIdx.x & 63;

    float w1c[K], w2c[K];
    #pragma unroll
    for (int j = 0; j < K; ++j) {
        w1c[j] = W1[j * K + lane];
        w2c[j] = W2[j * K + lane];
    }
    const float bias = b1[lane] + b2[lane];

    for (int node = blockIdx.x * 4 + wave; node < NN; node += gridDim.x * 4) {
        float xv = x[(size_t)node * K + lane];
        float sv = side[(size_t)node * K + lane];
        float p = sv + xv;
        float q = sv * xv;
        float acc = bias;
        #pragma unroll
        for (int j = 0; j < K; ++j) {
            acc = fmaf(__shfl(p, j), w1c[j], acc);
            acc = fmaf(__shfl(q, j), w2c[j], acc);
        }
        float h = (acc > 0.f) ? acc : SLOPE * acc;
        float ss = h * h;
        #pragma unroll
        for (int off = 32; off > 0; off >>= 1) ss += __shfl_xor(ss, off);
        float r = h / fmaxf(sqrtf(ss), EPS);
        y[(size_t)node * K + lane] = r;
        float rs = r;
        #pragma unroll
        for (int off = 32; off > 0; off >>= 1) rs += __shfl_xor(rs, off);
        if (lane == 0) gsum[node] += rs;   // one wave per node: no race
    }
}

// ---------------------------------------------------------------------------
// out[n] = gsum[n] / ((L+1)*K) = gsum[n] / 256
// ---------------------------------------------------------------------------
__global__ __launch_bounds__(256)
void finalize_kernel(const float* __restrict__ gsum, float* __restrict__ out) {
    int n = blockIdx.x * blockDim.x + threadIdx.x;
    if (n < NN) out[n] = gsum[n] * (1.0f / ((NL + 1) * K));
}

extern "C" void kernel_launch(void* const* d_in, const int* in_sizes, int n_in,
                              void* d_out, int out_size, void* d_ws, size_t ws_size,
                              hipStream_t stream) {
    const float* Gu = (const float*)d_in[0];
    const float* Gi = (const float*)d_in[1];
    const float* W1 = (const float*)d_in[2];   // [NL][K][K]
    const float* b1 = (const float*)d_in[3];   // [NL][K]
    const float* W2 = (const float*)d_in[4];
    const float* b2 = (const float*)d_in[5];
    const int*  edge = (const int*)d_in[6];    // [2][NE]
    float* out = (float*)d_out;

    // Workspace layout (4B elems): ebuf0 | ebuf1 | side | gsum | rowptr | bsum | cursor | cols
    float* ebuf0  = (float*)d_ws;
    float* ebuf1  = ebuf0 + (size_t)NN * K;
    float* side   = ebuf1 + (size_t)NN * K;
    float* gsum   = side  + (size_t)NN * K;
    int*   rowptr = (int*)(gsum + NN);
    int*   bsum   = rowptr + (NN + 1);
    int*   cursor = bsum + 512;
    int*   cols   = cursor + NN;

    const int* eu = edge;
    const int* ei = edge + NE;

    // --- CSR build (once per launch) ---
    hipMemsetAsync(rowptr, 0, (size_t)(NN + 1) * sizeof(int), stream);
    hist_kernel <<<(NE + 255) / 256, 256, 0, stream>>>(eu, ei, rowptr);
    scan1_kernel<<<NBLK, SCAN_B, 0, stream>>>(rowptr + 1, bsum);
    scan2_kernel<<<1, 512, 0, stream>>>(bsum);
    scan3_kernel<<<NBLK, SCAN_B, 0, stream>>>(rowptr, bsum, cursor);
    fill_kernel <<<(NE + 255) / 256, 256, 0, stream>>>(eu, ei, cursor, cols);

    // --- embeddings ---
    norm_init_kernel<<<(NN + 3) / 4, 256, 0, stream>>>(Gu, Gi, ebuf0, gsum);

    float* cur = ebuf0;
    float* nxt = ebuf1;
    for (int l = 0; l < NL; ++l) {
        gather_kernel<<<(NN + 3) / 4, 256, 0, stream>>>(rowptr, cols, cur, side);
        layer_kernel<<<2048, 256, 0, stream>>>(cur, side,
                                               W1 + (size_t)l * K * K, b1 + (size_t)l * K,
                                               W2 + (size_t)l * K * K, b2 + (size_t)l * K,
                                               nxt, gsum);
        float* t = cur; cur = nxt; nxt = t;
    }

    finalize_kernel<<<(NN + 255) / 256, 256, 0, stream>>>(gsum, out);
}

// Round 6
// 858.596 us; speedup vs baseline: 1.5915x; 1.4007x over previous
//
#include <hip/hip_runtime.h>
#include <hip/hip_bf16.h>

// Problem constants (from the reference)
constexpr int NU = 80000;    // users
constexpr int NI = 40000;    // items
constexpr int K  = 64;       // feature dim (== wavefront size, 1 lane per k)
constexpr int NL = 3;        // layers
constexpr int NN = NU + NI;  // 120000 nodes
constexpr int NE = 1000000;  // edges (undirected; each contributes both dirs)
constexpr float EPS   = 1e-12f;
constexpr float SLOPE = 0.01f;

constexpr int SCAN_B = 256;
constexpr int NBLK   = (NN + SCAN_B - 1) / SCAN_B;   // 469 scan blocks

// broadcast lane l's value to all lanes via v_readlane -> SGPR operand
__device__ __forceinline__ float bcast(float v, int l) {
    return __uint_as_float(__builtin_amdgcn_readlane(__float_as_uint(v), l));
}

// ---------------------------------------------------------------------------
// Kernel 1: e0 = l2norm(concat(Gu, Gi)); gsum[n] = rowsum(e0)
// ---------------------------------------------------------------------------
__global__ __launch_bounds__(256)
void norm_init_kernel(const float* __restrict__ Gu, const float* __restrict__ Gi,
                      float* __restrict__ e, float* __restrict__ gsum) {
    int node = blockIdx.x * 4 + (threadIdx.x >> 6);
    int lane = threadIdx.x & 63;
    if (node >= NN) return;
    float v = (node < NU) ? Gu[node * K + lane] : Gi[(node - NU) * K + lane];
    float ss = v * v;
    #pragma unroll
    for (int off = 32; off > 0; off >>= 1) ss += __shfl_xor(ss, off);
    float r = v / fmaxf(sqrtf(ss), EPS);
    e[node * K + lane] = r;
    float rs = r;
    #pragma unroll
    for (int off = 32; off > 0; off >>= 1) rs += __shfl_xor(rs, off);
    if (lane == 0) gsum[node] = rs;   // overwrite poison
}

// ---------------------------------------------------------------------------
// CSR build: histogram -> hierarchical exclusive scan -> ticket fill.
// ---------------------------------------------------------------------------
__global__ __launch_bounds__(256)
void hist_kernel(const int* __restrict__ eu, const int* __restrict__ ei,
                 int* __restrict__ rowptr) {
    int e = blockIdx.x * blockDim.x + threadIdx.x;
    if (e >= NE) return;
    atomicAdd(&rowptr[1 + eu[e]], 1);
    atomicAdd(&rowptr[1 + ei[e]], 1);
}

__global__ __launch_bounds__(SCAN_B)
void scan1_kernel(int* __restrict__ cnt, int* __restrict__ bsum) {
    __shared__ int sh[SCAN_B];
    int i = blockIdx.x * SCAN_B + threadIdx.x;
    int v = (i < NN) ? cnt[i] : 0;
    sh[threadIdx.x] = v;
    __syncthreads();
    #pragma unroll
    for (int off = 1; off < SCAN_B; off <<= 1) {
        int t = (threadIdx.x >= off) ? sh[threadIdx.x - off] : 0;
        __syncthreads();
        sh[threadIdx.x] += t;
        __syncthreads();
    }
    if (i < NN) cnt[i] = sh[threadIdx.x];
    if (threadIdx.x == SCAN_B - 1) bsum[blockIdx.x] = sh[SCAN_B - 1];
}

__global__ __launch_bounds__(512)
void scan2_kernel(int* __restrict__ bsum) {
    __shared__ int sh[512];
    int v = (threadIdx.x < NBLK) ? bsum[threadIdx.x] : 0;
    sh[threadIdx.x] = v;
    __syncthreads();
    #pragma unroll
    for (int off = 1; off < 512; off <<= 1) {
        int t = (threadIdx.x >= off) ? sh[threadIdx.x - off] : 0;
        __syncthreads();
        sh[threadIdx.x] += t;
        __syncthreads();
    }
    if (threadIdx.x < NBLK) bsum[threadIdx.x] = sh[threadIdx.x] - v; // exclusive
}

__global__ __launch_bounds__(SCAN_B)
void scan3_kernel(int* __restrict__ rowptr, const int* __restrict__ bsum,
                  int* __restrict__ cursor) {
    int i = blockIdx.x * SCAN_B + threadIdx.x;   // index into cnt = rowptr+1
    if (i < NN) {
        int v = rowptr[1 + i] + bsum[blockIdx.x];
        rowptr[1 + i] = v;                        // rowptr[i+1] final
        if (i + 1 < NN) cursor[i + 1] = v;        // start of node i+1
    }
    if (i == 0) cursor[0] = 0;
}

__global__ __launch_bounds__(256)
void fill_kernel(const int* __restrict__ eu, const int* __restrict__ ei,
                 int* __restrict__ cursor, int* __restrict__ cols) {
    int e = blockIdx.x * blockDim.x + threadIdx.x;
    if (e >= NE) return;
    int u = eu[e];
    int i = ei[e];
    int p = atomicAdd(&cursor[u], 1);
    cols[p] = i;
    int q = atomicAdd(&cursor[i], 1);
    cols[q] = u;
}

// ---------------------------------------------------------------------------
// Gather SpMM: side[n] = sum_{j in adj(n)} x[j].  One wave per node, no
// atomics, write-once. 4 VGPR -> ~max occupancy; TLP hides L2/L3 miss latency.
// ---------------------------------------------------------------------------
__global__ __launch_bounds__(256)
void gather_kernel(const int* __restrict__ rowptr, const int* __restrict__ cols,
                   const float* __restrict__ x, float* __restrict__ side) {
    int node = blockIdx.x * 4 + (threadIdx.x >> 6);
    int lane = threadIdx.x & 63;
    if (node >= NN) return;
    int s = rowptr[node];
    int e = rowptr[node + 1];
    float a0 = 0.f, a1 = 0.f, a2 = 0.f, a3 = 0.f;
    int t = s;
    for (; t + 4 <= e; t += 4) {
        int n0 = cols[t];
        int n1 = cols[t + 1];
        int n2 = cols[t + 2];
        int n3 = cols[t + 3];
        a0 += x[(size_t)n0 * K + lane];
        a1 += x[(size_t)n1 * K + lane];
        a2 += x[(size_t)n2 * K + lane];
        a3 += x[(size_t)n3 * K + lane];
    }
    for (; t < e; ++t) a0 += x[(size_t)cols[t] * K + lane];
    side[(size_t)node * K + lane] = (a0 + a1) + (a2 + a3);
}

// ---------------------------------------------------------------------------
// Dense layer, register-GEMV v2:
//   p = side + x ; q = side * x
//   h = p@W1 + b1 + q@W2 + b2 ; y = l2norm(leaky_relu(h)) ; gsum += rowsum(y)
// Lane holds weight columns W1[:,lane], W2[:,lane] in 128 VGPRs.
// p[j]/q[j] broadcast via explicit v_readlane (NOT __shfl -> ds_bpermute),
// folded as the SGPR operand of v_fma_f32. Four independent accumulator
// chains (j strided by 4) give the ILP to cover FMA latency at issue rate.
// ---------------------------------------------------------------------------
__global__ __launch_bounds__(256)
void layer_kernel(const float* __restrict__ x, const float* __restrict__ side,
                  const float* __restrict__ W1, const float* __restrict__ b1,
                  const float* __restrict__ W2, const float* __restrict__ b2,
                  float* __restrict__ y, float* __restrict__ gsum) {
    const int wave = threadIdx.x >> 6;
    const int lane = threadIdx.x & 63;

    float w1c[K], w2c[K];
    #pragma unroll
    for (int j = 0; j < K; ++j) {
        w1c[j] = W1[j * K + lane];
        w2c[j] = W2[j * K + lane];
    }
    const float bias = b1[lane] + b2[lane];

    for (int node = blockIdx.x * 4 + wave; node < NN; node += gridDim.x * 4) {
        float xv = x[(size_t)node * K + lane];
        float sv = side[(size_t)node * K + lane];
        float p = sv + xv;
        float q = sv * xv;
        float acc0 = bias, acc1 = 0.f, acc2 = 0.f, acc3 = 0.f;
        #pragma unroll
        for (int j = 0; j < K; j += 4) {
            acc0 = fmaf(bcast(p, j + 0), w1c[j + 0], acc0);
            acc0 = fmaf(bcast(q, j + 0), w2c[j + 0], acc0);
            acc1 = fmaf(bcast(p, j + 1), w1c[j + 1], acc1);
            acc1 = fmaf(bcast(q, j + 1), w2c[j + 1], acc1);
            acc2 = fmaf(bcast(p, j + 2), w1c[j + 2], acc2);
            acc2 = fmaf(bcast(q, j + 2), w2c[j + 2], acc2);
            acc3 = fmaf(bcast(p, j + 3), w1c[j + 3], acc3);
            acc3 = fmaf(bcast(q, j + 3), w2c[j + 3], acc3);
        }
        float acc = (acc0 + acc1) + (acc2 + acc3);

        float h = (acc > 0.f) ? acc : SLOPE * acc;
        float ss = h * h;
        #pragma unroll
        for (int off = 32; off > 0; off >>= 1) ss += __shfl_xor(ss, off);
        float r = h / fmaxf(sqrtf(ss), EPS);
        y[(size_t)node * K + lane] = r;
        float rs = r;
        #pragma unroll
        for (int off = 32; off > 0; off >>= 1) rs += __shfl_xor(rs, off);
        if (lane == 0) gsum[node] += rs;   // one wave per node: no race
    }
}

// ---------------------------------------------------------------------------
// out[n] = gsum[n] / ((L+1)*K) = gsum[n] / 256
// ---------------------------------------------------------------------------
__global__ __launch_bounds__(256)
void finalize_kernel(const float* __restrict__ gsum, float* __restrict__ out) {
    int n = blockIdx.x * blockDim.x + threadIdx.x;
    if (n < NN) out[n] = gsum[n] * (1.0f / ((NL + 1) * K));
}

extern "C" void kernel_launch(void* const* d_in, const int* in_sizes, int n_in,
                              void* d_out, int out_size, void* d_ws, size_t ws_size,
                              hipStream_t stream) {
    const float* Gu = (const float*)d_in[0];
    const float* Gi = (const float*)d_in[1];
    const float* W1 = (const float*)d_in[2];   // [NL][K][K]
    const float* b1 = (const float*)d_in[3];   // [NL][K]
    const float* W2 = (const float*)d_in[4];
    const float* b2 = (const float*)d_in[5];
    const int*  edge = (const int*)d_in[6];    // [2][NE]
    float* out = (float*)d_out;

    // Workspace layout (4B elems): ebuf0 | ebuf1 | side | gsum | rowptr | bsum | cursor | cols
    float* ebuf0  = (float*)d_ws;
    float* ebuf1  = ebuf0 + (size_t)NN * K;
    float* side   = ebuf1 + (size_t)NN * K;
    float* gsum   = side  + (size_t)NN * K;
    int*   rowptr = (int*)(gsum + NN);
    int*   bsum   = rowptr + (NN + 1);
    int*   cursor = bsum + 512;
    int*   cols   = cursor + NN;

    const int* eu = edge;
    const int* ei = edge + NE;

    // --- CSR build (once per launch) ---
    hipMemsetAsync(rowptr, 0, (size_t)(NN + 1) * sizeof(int), stream);
    hist_kernel <<<(NE + 255) / 256, 256, 0, stream>>>(eu, ei, rowptr);
    scan1_kernel<<<NBLK, SCAN_B, 0, stream>>>(rowptr + 1, bsum);
    scan2_kernel<<<1, 512, 0, stream>>>(bsum);
    scan3_kernel<<<NBLK, SCAN_B, 0, stream>>>(rowptr, bsum, cursor);
    fill_kernel <<<(NE + 255) / 256, 256, 0, stream>>>(eu, ei, cursor, cols);

    // --- embeddings ---
    norm_init_kernel<<<(NN + 3) / 4, 256, 0, stream>>>(Gu, Gi, ebuf0, gsum);

    float* cur = ebuf0;
    float* nxt = ebuf1;
    for (int l = 0; l < NL; ++l) {
        gather_kernel<<<(NN + 3) / 4, 256, 0, stream>>>(rowptr, cols, cur, side);
        layer_kernel<<<1024, 256, 0, stream>>>(cur, side,
                                               W1 + (size_t)l * K * K, b1 + (size_t)l * K,
                                               W2 + (size_t)l * K * K, b2 + (size_t)l * K,
                                               nxt, gsum);
        float* t = cur; cur = nxt; nxt = t;
    }

    finalize_kernel<<<(NN + 255) / 256, 256, 0, stream>>>(gsum, out);
}

// Round 9
// 856.134 us; speedup vs baseline: 1.5961x; 1.0029x over previous
//
#include <hip/hip_runtime.h>
#include <hip/hip_bf16.h>
#include <hip/hip_fp16.h>

// Problem constants (from the reference)
constexpr int NU = 80000;    // users
constexpr int NI = 40000;    // items
constexpr int K  = 64;       // feature dim (== wavefront size, 1 lane per k)
constexpr int NL = 3;        // layers
constexpr int NN = NU + NI;  // 120000 nodes
constexpr int NE = 1000000;  // edges (undirected; each contributes both dirs)
constexpr float EPS   = 1e-12f;
constexpr float SLOPE = 0.01f;

constexpr int SCAN_B = 256;
constexpr int NBLK   = (NN + SCAN_B - 1) / SCAN_B;   // 469 scan blocks

// broadcast lane l's value to all lanes via v_readlane -> SGPR operand
__device__ __forceinline__ float bcast(float v, int l) {
    return __uint_as_float(__builtin_amdgcn_readlane(__float_as_uint(v), l));
}

// ---------------------------------------------------------------------------
// Kernel 1: e0 = l2norm(concat(Gu, Gi)) stored fp16; gsum[n] = rowsum(e0)
// Compute is f32; only the inter-kernel embedding buffer is fp16 (|x|<=1,
// well inside fp16 range; storage rounding ~5e-4 relative).
// ---------------------------------------------------------------------------
__global__ __launch_bounds__(256)
void norm_init_kernel(const float* __restrict__ Gu, const float* __restrict__ Gi,
                      __half* __restrict__ e, float* __restrict__ gsum) {
    int node = blockIdx.x * 4 + (threadIdx.x >> 6);
    int lane = threadIdx.x & 63;
    if (node >= NN) return;
    float v = (node < NU) ? Gu[node * K + lane] : Gi[(node - NU) * K + lane];
    float ss = v * v;
    #pragma unroll
    for (int off = 32; off > 0; off >>= 1) ss += __shfl_xor(ss, off);
    float r = v / fmaxf(sqrtf(ss), EPS);
    e[(size_t)node * K + lane] = __float2half(r);
    float rs = r;
    #pragma unroll
    for (int off = 32; off > 0; off >>= 1) rs += __shfl_xor(rs, off);
    if (lane == 0) gsum[node] = rs;   // overwrite poison
}

// ---------------------------------------------------------------------------
// CSR build: histogram -> hierarchical exclusive scan -> ticket fill.
// ---------------------------------------------------------------------------
__global__ __launch_bounds__(256)
void hist_kernel(const int* __restrict__ eu, const int* __restrict__ ei,
                 int* __restrict__ rowptr) {
    int e = blockIdx.x * blockDim.x + threadIdx.x;
    if (e >= NE) return;
    atomicAdd(&rowptr[1 + eu[e]], 1);
    atomicAdd(&rowptr[1 + ei[e]], 1);
}

__global__ __launch_bounds__(SCAN_B)
void scan1_kernel(int* __restrict__ cnt, int* __restrict__ bsum) {
    __shared__ int sh[SCAN_B];
    int i = blockIdx.x * SCAN_B + threadIdx.x;
    int v = (i < NN) ? cnt[i] : 0;
    sh[threadIdx.x] = v;
    __syncthreads();
    #pragma unroll
    for (int off = 1; off < SCAN_B; off <<= 1) {
        int t = (threadIdx.x >= off) ? sh[threadIdx.x - off] : 0;
        __syncthreads();
        sh[threadIdx.x] += t;
        __syncthreads();
    }
    if (i < NN) cnt[i] = sh[threadIdx.x];
    if (threadIdx.x == SCAN_B - 1) bsum[blockIdx.x] = sh[SCAN_B - 1];
}

__global__ __launch_bounds__(512)
void scan2_kernel(int* __restrict__ bsum) {
    __shared__ int sh[512];
    int v = (threadIdx.x < NBLK) ? bsum[threadIdx.x] : 0;
    sh[threadIdx.x] = v;
    __syncthreads();
    #pragma unroll
    for (int off = 1; off < 512; off <<= 1) {
        int t = (threadIdx.x >= off) ? sh[threadIdx.x - off] : 0;
        __syncthreads();
        sh[threadIdx.x] += t;
        __syncthreads();
    }
    if (threadIdx.x < NBLK) bsum[threadIdx.x] = sh[threadIdx.x] - v; // exclusive
}

__global__ __launch_bounds__(SCAN_B)
void scan3_kernel(int* __restrict__ rowptr, const int* __restrict__ bsum,
                  int* __restrict__ cursor) {
    int i = blockIdx.x * SCAN_B + threadIdx.x;   // index into cnt = rowptr+1
    if (i < NN) {
        int v = rowptr[1 + i] + bsum[blockIdx.x];
        rowptr[1 + i] = v;                        // rowptr[i+1] final
        if (i + 1 < NN) cursor[i + 1] = v;        // start of node i+1
    }
    if (i == 0) cursor[0] = 0;
}

__global__ __launch_bounds__(256)
void fill_kernel(const int* __restrict__ eu, const int* __restrict__ ei,
                 int* __restrict__ cursor, int* __restrict__ cols) {
    int e = blockIdx.x * blockDim.x + threadIdx.x;
    if (e >= NE) return;
    int u = eu[e];
    int i = ei[e];
    int p = atomicAdd(&cursor[u], 1);
    cols[p] = i;
    int q = atomicAdd(&cursor[i], 1);
    cols[q] = u;
}

// ---------------------------------------------------------------------------
// Gather SpMM: side[n] = sum_{j in adj(n)} x[j] (x in fp16 -> 128B/row).
// One wave per node, no atomics, f32 accumulation, write-once f32 side.
// 4 VGPR-ish -> high occupancy; TLP hides L2/L3 miss latency.
// ---------------------------------------------------------------------------
__global__ __launch_bounds__(256)
void gather_kernel(const int* __restrict__ rowptr, const int* __restrict__ cols,
                   const __half* __restrict__ x, float* __restrict__ side) {
    int node = blockIdx.x * 4 + (threadIdx.x >> 6);
    int lane = threadIdx.x & 63;
    if (node >= NN) return;
    int s = rowptr[node];
    int e = rowptr[node + 1];
    float a0 = 0.f, a1 = 0.f, a2 = 0.f, a3 = 0.f;
    int t = s;
    for (; t + 4 <= e; t += 4) {
        int n0 = cols[t];
        int n1 = cols[t + 1];
        int n2 = cols[t + 2];
        int n3 = cols[t + 3];
        a0 += __half2float(x[(size_t)n0 * K + lane]);
        a1 += __half2float(x[(size_t)n1 * K + lane]);
        a2 += __half2float(x[(size_t)n2 * K + lane]);
        a3 += __half2float(x[(size_t)n3 * K + lane]);
    }
    for (; t < e; ++t) a0 += __half2float(x[(size_t)cols[t] * K + lane]);
    side[(size_t)node * K + lane] = (a0 + a1) + (a2 + a3);
}

// ---------------------------------------------------------------------------
// Dense layer, register-GEMV v2 (fp16 x in, fp16 y out, f32 compute):
//   p = side + x ; q = side * x
//   h = p@W1 + b1 + q@W2 + b2 ; y = l2norm(leaky_relu(h)) ; gsum += rowsum(y)
// Lane holds weight columns W1[:,lane], W2[:,lane] in 128 VGPRs.
// p[j]/q[j] broadcast via explicit v_readlane, folded as the SGPR operand of
// v_fma_f32. Four independent accumulator chains cover FMA latency.
// ---------------------------------------------------------------------------
__global__ __launch_bounds__(256)
void layer_kernel(const __half* __restrict__ x, const float* __restrict__ side,
                  const float* __restrict__ W1, const float* __restrict__ b1,
                  const float* __restrict__ W2, const float* __restrict__ b2,
                  __half* __restrict__ y, float* __restrict__ gsum) {
    const int wave = threadIdx.x >> 6;
    const int lane = threadIdx.x & 63;

    float w1c[K], w2c[K];
    #pragma unroll
    for (int j = 0; j < K; ++j) {
        w1c[j] = W1[j * K + lane];
        w2c[j] = W2[j * K + lane];
    }
    const float bias = b1[lane] + b2[lane];

    for (int node = blockIdx.x * 4 + wave; node < NN; node += gridDim.x * 4) {
        float xv = __half2float(x[(size_t)node * K + lane]);
        float sv = side[(size_t)node * K + lane];
        float p = sv + xv;
        float q = sv * xv;
        float acc0 = bias, acc1 = 0.f, acc2 = 0.f, acc3 = 0.f;
        #pragma unroll
        for (int j = 0; j < K; j += 4) {
            acc0 = fmaf(bcast(p, j + 0), w1c[j + 0], acc0);
            acc0 = fmaf(bcast(q, j + 0), w2c[j + 0], acc0);
            acc1 = fmaf(bcast(p, j + 1), w1c[j + 1], acc1);
            acc1 = fmaf(bcast(q, j + 1), w2c[j + 1], acc1);
            acc2 = fmaf(bcast(p, j + 2), w1c[j + 2], acc2);
            acc2 = fmaf(bcast(q, j + 2), w2c[j + 2], acc2);
            acc3 = fmaf(bcast(p, j + 3), w1c[j + 3], acc3);
            acc3 = fmaf(bcast(q, j + 3), w2c[j + 3], acc3);
        }
        float acc = (acc0 + acc1) + (acc2 + acc3);

        float h = (acc > 0.f) ? acc : SLOPE * acc;
        float ss = h * h;
        #pragma unroll
        for (int off = 32; off > 0; off >>= 1) ss += __shfl_xor(ss, off);
        float r = h / fmaxf(sqrtf(ss), EPS);
        y[(size_t)node * K + lane] = __float2half(r);
        float rs = r;
        #pragma unroll
        for (int off = 32; off > 0; off >>= 1) rs += __shfl_xor(rs, off);
        if (lane == 0) gsum[node] += rs;   // one wave per node: no race
    }
}

// ---------------------------------------------------------------------------
// out[n] = gsum[n] / ((L+1)*K) = gsum[n] / 256
// ---------------------------------------------------------------------------
__global__ __launch_bounds__(256)
void finalize_kernel(const float* __restrict__ gsum, float* __restrict__ out) {
    int n = blockIdx.x * blockDim.x + threadIdx.x;
    if (n < NN) out[n] = gsum[n] * (1.0f / ((NL + 1) * K));
}

extern "C" void kernel_launch(void* const* d_in, const int* in_sizes, int n_in,
                              void* d_out, int out_size, void* d_ws, size_t ws_size,
                              hipStream_t stream) {
    const float* Gu = (const float*)d_in[0];
    const float* Gi = (const float*)d_in[1];
    const float* W1 = (const float*)d_in[2];   // [NL][K][K]
    const float* b1 = (const float*)d_in[3];   // [NL][K]
    const float* W2 = (const float*)d_in[4];
    const float* b2 = (const float*)d_in[5];
    const int*  edge = (const int*)d_in[6];    // [2][NE]
    float* out = (float*)d_out;

    // Workspace layout: xbuf0(half) | xbuf1(half) | side(f32) | gsum(f32) |
    //                   rowptr | bsum | cursor | cols   (~78 MB total)
    __half* xbuf0 = (__half*)d_ws;
    __half* xbuf1 = xbuf0 + (size_t)NN * K;
    float*  side  = (float*)(xbuf1 + (size_t)NN * K);
    float*  gsum  = side + (size_t)NN * K;
    int*    rowptr = (int*)(gsum + NN);
    int*    bsum   = rowptr + (NN + 1);
    int*    cursor = bsum + 512;
    int*    cols   = cursor + NN;

    const int* eu = edge;
    const int* ei = edge + NE;

    // --- CSR build (once per launch) ---
    hipMemsetAsync(rowptr, 0, (size_t)(NN + 1) * sizeof(int), stream);
    hist_kernel <<<(NE + 255) / 256, 256, 0, stream>>>(eu, ei, rowptr);
    scan1_kernel<<<NBLK, SCAN_B, 0, stream>>>(rowptr + 1, bsum);
    scan2_kernel<<<1, 512, 0, stream>>>(bsum);
    scan3_kernel<<<NBLK, SCAN_B, 0, stream>>>(rowptr, bsum, cursor);
    fill_kernel <<<(NE + 255) / 256, 256, 0, stream>>>(eu, ei, cursor, cols);

    // --- embeddings ---
    norm_init_kernel<<<(NN + 3) / 4, 256, 0, stream>>>(Gu, Gi, xbuf0, gsum);

    __half* cur = xbuf0;
    __half* nxt = xbuf1;
    for (int l = 0; l < NL; ++l) {
        gather_kernel<<<(NN + 3) / 4, 256, 0, stream>>>(rowptr, cols, cur, side);
        layer_kernel<<<1024, 256, 0, stream>>>(cur, side,
                                               W1 + (size_t)l * K * K, b1 + (size_t)l * K,
                                               W2 + (size_t)l * K * K, b2 + (size_t)l * K,
                                               nxt, gsum);
        __half* t = cur; cur = nxt; nxt = t;
    }

    finalize_kernel<<<(NN + 255) / 256, 256, 0, stream>>>(gsum, out);
}